// Round 2
// baseline (452.792 us; speedup 1.0000x reference)
//
#include <hip/hip_runtime.h>

typedef float f4 __attribute__((ext_vector_type(4)));

__global__ __launch_bounds__(256) void zero_i32(int* __restrict__ p, int n) {
    int i = blockIdx.x * 256 + threadIdx.x;
    if (i < n) p[i] = 0;
}

__global__ __launch_bounds__(256) void degree_kernel(const int* __restrict__ dst,
                                                     int* __restrict__ deg, int E) {
    int e = blockIdx.x * 256 + threadIdx.x;
    if (e < E) atomicAdd(&deg[dst[e]], 1);
}

// Single-block exclusive scan of deg[0..N-1] -> row_ptr[0..N], also copies to cursor.
// 1024 threads = 16 waves; wave-level shfl scan + LDS combine (3 barriers/chunk).
__global__ __launch_bounds__(1024) void scan_kernel(const int* __restrict__ deg,
                                                    int* __restrict__ row_ptr,
                                                    int* __restrict__ cursor, int N) {
    __shared__ int wsum[16];
    __shared__ int wpre[16];
    const int tid = threadIdx.x;
    const int lane = tid & 63;
    const int w = tid >> 6;
    int carry = 0;
    for (int base = 0; base < N; base += 1024) {
        int i = base + tid;
        int v = (i < N) ? deg[i] : 0;
        int x = v;
        #pragma unroll
        for (int off = 1; off < 64; off <<= 1) {
            int t = __shfl_up(x, off, 64);
            if (lane >= off) x += t;
        }
        if (lane == 63) wsum[w] = x;
        __syncthreads();
        if (w == 0) {
            int s = (lane < 16) ? wsum[lane] : 0;
            #pragma unroll
            for (int off = 1; off < 16; off <<= 1) {
                int t = __shfl_up(s, off, 64);
                if (lane >= off) s += t;
            }
            if (lane < 16) wpre[lane] = s;  // inclusive scan of wave sums
        }
        __syncthreads();
        int wave_excl = (w == 0) ? 0 : wpre[w - 1];
        int excl = carry + wave_excl + x - v;
        if (i < N) { row_ptr[i] = excl; cursor[i] = excl; }
        carry += wpre[15];
        __syncthreads();  // protect wsum/wpre before next chunk overwrites
    }
    if (tid == 0) row_ptr[N] = carry;
}

__global__ __launch_bounds__(256) void scatter_kernel(const int* __restrict__ src,
                                                      const int* __restrict__ dst,
                                                      int* __restrict__ cursor,
                                                      int* __restrict__ ssrc, int E) {
    int e = blockIdx.x * 256 + threadIdx.x;
    if (e < E) {
        int d = dst[e];
        int pos = atomicAdd(&cursor[d], 1);
        ssrc[pos] = src[e];
    }
}

// One 32-lane group per node; each lane owns 4 consecutive floats (float4) of the
// 128-wide feature row. Mean over in-neighbors, degree clamped to 1.
// Unroll-4 for memory-level parallelism (4 gathered rows in flight per group).
__global__ __launch_bounds__(256) void agg_kernel(const float* __restrict__ h,
                                                  const int* __restrict__ row_ptr,
                                                  const int* __restrict__ ssrc,
                                                  float* __restrict__ out, int N) {
    int gid = (blockIdx.x * 256 + threadIdx.x) >> 5;
    int lane = threadIdx.x & 31;
    if (gid >= N) return;
    int start = row_ptr[gid];
    int end = row_ptr[gid + 1];
    f4 acc0 = {0.f, 0.f, 0.f, 0.f};
    f4 acc1 = {0.f, 0.f, 0.f, 0.f};
    int e = start;
    for (; e + 4 <= end; e += 4) {
        int s0 = ssrc[e];
        int s1 = ssrc[e + 1];
        int s2 = ssrc[e + 2];
        int s3 = ssrc[e + 3];
        f4 v0 = *(const f4*)(h + (size_t)s0 * 128 + lane * 4);
        f4 v1 = *(const f4*)(h + (size_t)s1 * 128 + lane * 4);
        f4 v2 = *(const f4*)(h + (size_t)s2 * 128 + lane * 4);
        f4 v3 = *(const f4*)(h + (size_t)s3 * 128 + lane * 4);
        acc0 += v0; acc1 += v1; acc0 += v2; acc1 += v3;
    }
    for (; e < end; ++e) {
        int s0 = ssrc[e];
        acc0 += *(const f4*)(h + (size_t)s0 * 128 + lane * 4);
    }
    f4 acc = acc0 + acc1;
    float inv = 1.0f / fmaxf((float)(end - start), 1.0f);
    acc *= inv;
    *(f4*)(out + (size_t)gid * 128 + lane * 4) = acc;
}

// Fused dual GEMM: out[r][c] = act(sum_k A[r][k]*Ws[k][c] + Bn[r][k]*Wn[k][c] + bias[c]).
// Block: 256 threads -> 64 rows x 64 cols (blockIdx.y selects which 64-col half).
// Thread: 4 consecutive rows (slot = tid>>4) x 4 cols ((tid&15)*4).
// Per j-step: 2 ds_read_b128 (24 cyc) feed 32 v_fma (64 cyc) -> LDS pipe hidden,
// kernel VALU-bound. Weight halves in LDS: 64 KB/block -> 2 blocks/CU.
template <int RELU>
__global__ __launch_bounds__(256, 2) void gemm_fused(const float* __restrict__ A,
                                                     const float* __restrict__ Bn,
                                                     const float* __restrict__ Ws,
                                                     const float* __restrict__ Wn,
                                                     const float* __restrict__ bias,
                                                     float* __restrict__ out, int N) {
    __shared__ float sWs[128][64];
    __shared__ float sWn[128][64];
    const int c0 = blockIdx.y * 64;
    for (int i = threadIdx.x; i < 128 * 16; i += 256) {
        int k = i >> 4;
        int j = i & 15;
        ((f4*)&sWs[k][0])[j] = *(const f4*)(Ws + k * 128 + c0 + j * 4);
        ((f4*)&sWn[k][0])[j] = *(const f4*)(Wn + k * 128 + c0 + j * 4);
    }
    __syncthreads();

    const int c = (threadIdx.x & 15) * 4;   // col within the 64-col half
    const int slot = threadIdx.x >> 4;      // 0..15 -> rows slot*4 .. slot*4+3
    const int row0 = blockIdx.x * 64 + slot * 4;
    f4 bv = *(const f4*)(bias + c0 + c);

    bool ok[4];
    const float* a[4];
    const float* n[4];
    #pragma unroll
    for (int i = 0; i < 4; ++i) {
        int r = row0 + i;
        ok[i] = r < N;
        a[i] = A + (size_t)(ok[i] ? r : 0) * 128;
        n[i] = Bn + (size_t)(ok[i] ? r : 0) * 128;
    }

    f4 acc[4];
    #pragma unroll
    for (int i = 0; i < 4; ++i) acc[i] = f4{0.f, 0.f, 0.f, 0.f};

    #pragma unroll 2
    for (int k = 0; k < 128; k += 4) {
        f4 av[4], nv[4];
        #pragma unroll
        for (int i = 0; i < 4; ++i) {
            av[i] = *(const f4*)(a[i] + k);
            nv[i] = *(const f4*)(n[i] + k);
        }
        #pragma unroll
        for (int j = 0; j < 4; ++j) {
            f4 ws = *(const f4*)&sWs[k + j][c];
            f4 wn = *(const f4*)&sWn[k + j][c];
            #pragma unroll
            for (int i = 0; i < 4; ++i) {
                acc[i] += av[i][j] * ws;
                acc[i] += nv[i][j] * wn;
            }
        }
    }

    #pragma unroll
    for (int i = 0; i < 4; ++i) {
        f4 o = acc[i] + bv;
        if (RELU) {
            #pragma unroll
            for (int j = 0; j < 4; ++j) o[j] = fmaxf(o[j], 0.f);
        }
        if (ok[i]) *(f4*)(out + (size_t)(row0 + i) * 128 + c0 + c) = o;
    }
}

extern "C" void kernel_launch(void* const* d_in, const int* in_sizes, int n_in,
                              void* d_out, int out_size, void* d_ws, size_t ws_size,
                              hipStream_t stream) {
    const float* x       = (const float*)d_in[0];
    const int*   src     = (const int*)d_in[1];
    const int*   dst     = (const int*)d_in[2];
    const float* Wself1  = (const float*)d_in[3];
    const float* Wneigh1 = (const float*)d_in[4];
    const float* b1      = (const float*)d_in[5];
    const float* Wself2  = (const float*)d_in[6];
    const float* Wneigh2 = (const float*)d_in[7];
    const float* b2      = (const float*)d_in[8];
    float* out = (float*)d_out;

    const int N = in_sizes[0] / 128;
    const int E = in_sizes[1];

    char* p = (char*)d_ws;
    auto alloc = [&](size_t bytes) {
        char* r = p;
        p += (bytes + 255) & ~(size_t)255;
        return r;
    };
    int*   deg     = (int*)alloc((size_t)N * 4);
    int*   row_ptr = (int*)alloc((size_t)(N + 1) * 4);
    int*   cursor  = (int*)alloc((size_t)N * 4);
    int*   ssrc    = (int*)alloc((size_t)E * 4);
    float* hn      = (float*)alloc((size_t)N * 128 * 4);
    float* h1      = (float*)alloc((size_t)N * 128 * 4);
    (void)ws_size;

    // CSR build (reused by both layers)
    zero_i32<<<(N + 255) / 256, 256, 0, stream>>>(deg, N);
    degree_kernel<<<(E + 255) / 256, 256, 0, stream>>>(dst, deg, E);
    scan_kernel<<<1, 1024, 0, stream>>>(deg, row_ptr, cursor, N);
    scatter_kernel<<<(E + 255) / 256, 256, 0, stream>>>(src, dst, cursor, ssrc, E);

    dim3 gemm_grid((N + 63) / 64, 2);
    int agg_blocks = (int)(((size_t)N * 32 + 255) / 256);

    // Layer 1: hn = mean_agg(x); h1 = relu(x@Ws1 + hn@Wn1 + b1)
    agg_kernel<<<agg_blocks, 256, 0, stream>>>(x, row_ptr, ssrc, hn, N);
    gemm_fused<1><<<gemm_grid, 256, 0, stream>>>(x, hn, Wself1, Wneigh1, b1, h1, N);

    // Layer 2: hn = mean_agg(h1); out = h1@Ws2 + hn@Wn2 + b2
    agg_kernel<<<agg_blocks, 256, 0, stream>>>(h1, row_ptr, ssrc, hn, N);
    gemm_fused<0><<<gemm_grid, 256, 0, stream>>>(h1, hn, Wself2, Wneigh2, b2, out, N);
}

// Round 8
// 334.510 us; speedup vs baseline: 1.3536x; 1.3536x over previous
//
#include <hip/hip_runtime.h>

typedef float f4 __attribute__((ext_vector_type(4)));
typedef short s8 __attribute__((ext_vector_type(8)));   // 8 bf16 = 4 VGPRs (MFMA A/B frag)
typedef float f32x4 __attribute__((ext_vector_type(4))); // MFMA C/D frag

__device__ __forceinline__ unsigned short f2bf(float x) {
    unsigned u = __builtin_bit_cast(unsigned, x);
    unsigned r = u + 0x7FFFu + ((u >> 16) & 1u);   // round-to-nearest-even
    return (unsigned short)(r >> 16);
}
__device__ __forceinline__ float bf2f(unsigned short h) {
    unsigned u = ((unsigned)h) << 16;
    return __builtin_bit_cast(float, u);
}

__global__ __launch_bounds__(256) void zero_i32(int* __restrict__ p, int n) {
    int i = blockIdx.x * 256 + threadIdx.x;
    if (i < n) p[i] = 0;
}

__global__ __launch_bounds__(256) void degree_kernel(const int* __restrict__ dst,
                                                     int* __restrict__ deg, int E) {
    int e = blockIdx.x * 256 + threadIdx.x;
    if (e < E) atomicAdd(&deg[dst[e]], 1);
}

// ---- 3-kernel multi-block scan (2048 elems/block in level 1) ----
__global__ __launch_bounds__(256) void scan1(const int* __restrict__ deg,
                                             int* __restrict__ part,
                                             int* __restrict__ bsum, int N) {
    __shared__ int wsum[4];
    const int t = threadIdx.x, lane = t & 63, w = t >> 6;
    const int base = blockIdx.x * 2048 + t * 8;
    int v[8], excl[8];
    int s = 0;
    #pragma unroll
    for (int j = 0; j < 8; ++j) {
        v[j] = (base + j < N) ? deg[base + j] : 0;
        excl[j] = s;
        s += v[j];
    }
    int x = s;  // wave inclusive scan of per-thread totals
    #pragma unroll
    for (int off = 1; off < 64; off <<= 1) {
        int tt = __shfl_up(x, off, 64);
        if (lane >= off) x += tt;
    }
    if (lane == 63) wsum[w] = x;
    __syncthreads();
    int woff = 0;
    for (int k = 0; k < 4; ++k) if (k < w) woff += wsum[k];
    int ebase = woff + (x - s);
    #pragma unroll
    for (int j = 0; j < 8; ++j)
        if (base + j < N) part[base + j] = ebase + excl[j];
    if (t == 255) bsum[blockIdx.x] = woff + x;
}

__global__ __launch_bounds__(64) void scan2(int* __restrict__ bsum,
                                            int* __restrict__ total_out, int nb) {
    int lane = threadIdx.x;
    int v = (lane < nb) ? bsum[lane] : 0;
    int x = v;
    #pragma unroll
    for (int off = 1; off < 64; off <<= 1) {
        int tt = __shfl_up(x, off, 64);
        if (lane >= off) x += tt;
    }
    if (lane < nb) bsum[lane] = x - v;  // exclusive
    if (lane == 63) total_out[0] = x;
}

__global__ __launch_bounds__(256) void scan3(const int* __restrict__ part,
                                             const int* __restrict__ bsum,
                                             int* __restrict__ row_ptr,
                                             int* __restrict__ cursor, int N) {
    int i = blockIdx.x * 256 + threadIdx.x;
    if (i < N) {
        int val = part[i] + bsum[i >> 11];
        row_ptr[i] = val;
        cursor[i] = val;
    }
}

__global__ __launch_bounds__(256) void scatter_kernel(const int* __restrict__ src,
                                                      const int* __restrict__ dst,
                                                      int* __restrict__ cursor,
                                                      int* __restrict__ ssrc, int E) {
    int e = blockIdx.x * 256 + threadIdx.x;
    if (e < E) {
        int d = dst[e];
        int pos = atomicAdd(&cursor[d], 1);
        ssrc[pos] = src[e];
    }
}

// One 32-lane group per node; lane owns float4 of the 128-wide row. Mean, deg>=1.
__global__ __launch_bounds__(256) void agg_kernel(const float* __restrict__ h,
                                                  const int* __restrict__ row_ptr,
                                                  const int* __restrict__ ssrc,
                                                  float* __restrict__ out, int N) {
    int gid = (blockIdx.x * 256 + threadIdx.x) >> 5;
    int lane = threadIdx.x & 31;
    if (gid >= N) return;
    int start = row_ptr[gid];
    int end = row_ptr[gid + 1];
    f4 acc0 = {0.f, 0.f, 0.f, 0.f};
    f4 acc1 = {0.f, 0.f, 0.f, 0.f};
    int e = start;
    for (; e + 4 <= end; e += 4) {
        int s0 = ssrc[e], s1 = ssrc[e + 1], s2 = ssrc[e + 2], s3 = ssrc[e + 3];
        f4 v0 = *(const f4*)(h + (size_t)s0 * 128 + lane * 4);
        f4 v1 = *(const f4*)(h + (size_t)s1 * 128 + lane * 4);
        f4 v2 = *(const f4*)(h + (size_t)s2 * 128 + lane * 4);
        f4 v3 = *(const f4*)(h + (size_t)s3 * 128 + lane * 4);
        acc0 += v0; acc1 += v1; acc0 += v2; acc1 += v3;
    }
    for (; e < end; ++e) {
        int s0 = ssrc[e];
        acc0 += *(const f4*)(h + (size_t)s0 * 128 + lane * 4);
    }
    f4 acc = acc0 + acc1;
    float inv = 1.0f / fmaxf((float)(end - start), 1.0f);
    acc *= inv;
    *(f4*)(out + (size_t)gid * 128 + lane * 4) = acc;
}

// Pack 4 weight matrices (f32 [128][128], row=k, col=n) into bf16 hi/lo MFMA
// B-fragment order: idx t = var*2048 + ks*512 + cf*64 + lane; element j of frag =
// bf16(W[ks*32 + (lane>>4)*8 + j][cf*16 + (lane&15)]). Same k-map as A-frags.
__global__ __launch_bounds__(256) void pack_w(const float* __restrict__ W0,
                                              const float* __restrict__ W1,
                                              const float* __restrict__ W2,
                                              const float* __restrict__ W3,
                                              unsigned short* __restrict__ O0,
                                              unsigned short* __restrict__ O1,
                                              unsigned short* __restrict__ O2,
                                              unsigned short* __restrict__ O3) {
    int t = blockIdx.x * 256 + threadIdx.x;   // 16384 total
    int lane = t & 63;
    int cf = (t >> 6) & 7;
    int ks = (t >> 9) & 3;
    int var = (t >> 11) & 1;
    int mat = t >> 12;
    const float* W = (mat == 0) ? W0 : (mat == 1) ? W1 : (mat == 2) ? W2 : W3;
    unsigned short* O = (mat == 0) ? O0 : (mat == 1) ? O1 : (mat == 2) ? O2 : O3;
    int col = cf * 16 + (lane & 15);
    int k0 = ks * 32 + (lane >> 4) * 8;
    unsigned short v[8];
    #pragma unroll
    for (int j = 0; j < 8; ++j) {
        float x = W[(size_t)(k0 + j) * 128 + col];
        unsigned short hi = f2bf(x);
        v[j] = var ? f2bf(x - bf2f(hi)) : hi;
    }
    *(s8*)(O + (size_t)(t & 4095) * 8) = *(s8*)v;
}

// bf16x3 MFMA GEMM: out[r][:] = act(A[r]@Ws + An[r]@Wn + bias).
// Block: 256 thr (4 waves), 64 rows x 128 cols. Wave w: cols w*32..w*32+32, all rows.
// A/An split to bf16 hi/lo and staged in LDS in A-fragment order (XOR-swizzled).
// Fragment conventions (cancel-by-construction k-map, measured C/D map):
//   A: lane&15 = row, k = (lane>>4)*8 + j ; B: lane&15 = col, same k-map
//   C/D: col = lane&15, row = (lane>>4)*4 + q
template <int RELU>
__global__ __launch_bounds__(256, 2) void gemm_mfma(const float* __restrict__ A,
                                                    const float* __restrict__ An,
                                                    const unsigned short* __restrict__ WsPk,
                                                    const unsigned short* __restrict__ WnPk,
                                                    const float* __restrict__ bias,
                                                    float* __restrict__ out, int N) {
    __shared__ short lds[32768];  // [mat2][var2][ks4][rf4][lane64][8 bf16] = 64 KB
    const int row0 = blockIdx.x * 64;
    const int tid = threadIdx.x;

    // ---- stage A/An as bf16 hi/lo in fragment order ----
    #pragma unroll
    for (int it = 0; it < 8; ++it) {
        int idx = tid + it * 256;           // 0..2047
        int mat = idx >> 10;
        int g = idx & 1023;
        int r = g >> 4;                     // row in tile
        int cg = g & 15;                    // 8-col group
        int row = row0 + r;
        if (row >= N) row = N - 1;
        const float* srcp = mat ? An : A;
        f4 v0 = *(const f4*)(srcp + (size_t)row * 128 + cg * 8);
        f4 v1 = *(const f4*)(srcp + (size_t)row * 128 + cg * 8 + 4);
        unsigned short hi[8], lo[8];
        #pragma unroll
        for (int j = 0; j < 4; ++j) {
            hi[j] = f2bf(v0[j]);
            lo[j] = f2bf(v0[j] - bf2f(hi[j]));
            hi[4 + j] = f2bf(v1[j]);
            lo[4 + j] = f2bf(v1[j] - bf2f(hi[4 + j]));
        }
        int ks = cg >> 2, rf = r >> 4;
        int lane_f = ((cg & 3) << 4) | (r & 15);
        int u_hi = ((mat * 2 + 0) * 16 + ks * 4 + rf) * 64 + lane_f;
        int u_lo = ((mat * 2 + 1) * 16 + ks * 4 + rf) * 64 + lane_f;
        u_hi ^= (u_hi >> 4) & 3;
        u_lo ^= (u_lo >> 4) & 3;
        *(s8*)(lds + (size_t)u_hi * 8) = *(s8*)hi;
        *(s8*)(lds + (size_t)u_lo * 8) = *(s8*)lo;
    }
    __syncthreads();

    const int l = tid & 63;
    const int w = tid >> 6;
    f32x4 acc[4][2];
    #pragma unroll
    for (int rf = 0; rf < 4; ++rf)
        #pragma unroll
        for (int c = 0; c < 2; ++c) acc[rf][c] = f32x4{0.f, 0.f, 0.f, 0.f};

    const unsigned short* wpk[2] = {WsPk, WnPk};

    #pragma unroll
    for (int ks = 0; ks < 4; ++ks) {
        s8 bfrag[2][2][2];  // [cfi][mat][var]
        #pragma unroll
        for (int cfi = 0; cfi < 2; ++cfi)
            #pragma unroll
            for (int mat = 0; mat < 2; ++mat)
                #pragma unroll
                for (int var = 0; var < 2; ++var) {
                    int cf = w * 2 + cfi;
                    bfrag[cfi][mat][var] = *(const s8*)(wpk[mat] +
                        ((size_t)((var * 4 + ks) * 8 + cf) * 64 + l) * 8);
                }
        s8 afrag[2][2][4];  // [mat][var][rf]
        #pragma unroll
        for (int mat = 0; mat < 2; ++mat)
            #pragma unroll
            for (int var = 0; var < 2; ++var)
                #pragma unroll
                for (int rf = 0; rf < 4; ++rf) {
                    int u = ((mat * 2 + var) * 16 + ks * 4 + rf) * 64 + l;
                    u ^= (u >> 4) & 3;
                    afrag[mat][var][rf] = *(const s8*)(lds + (size_t)u * 8);
                }
        #pragma unroll
        for (int rf = 0; rf < 4; ++rf)
            #pragma unroll
            for (int cfi = 0; cfi < 2; ++cfi)
                #pragma unroll
                for (int mat = 0; mat < 2; ++mat) {
                    acc[rf][cfi] = __builtin_amdgcn_mfma_f32_16x16x32_bf16(
                        afrag[mat][0][rf], bfrag[cfi][mat][0], acc[rf][cfi], 0, 0, 0);
                    acc[rf][cfi] = __builtin_amdgcn_mfma_f32_16x16x32_bf16(
                        afrag[mat][0][rf], bfrag[cfi][mat][1], acc[rf][cfi], 0, 0, 0);
                    acc[rf][cfi] = __builtin_amdgcn_mfma_f32_16x16x32_bf16(
                        afrag[mat][1][rf], bfrag[cfi][mat][0], acc[rf][cfi], 0, 0, 0);
                }
    }

    #pragma unroll
    for (int rf = 0; rf < 4; ++rf)
        #pragma unroll
        for (int cfi = 0; cfi < 2; ++cfi) {
            int col = w * 32 + cfi * 16 + (l & 15);
            float bv = bias[col];
            #pragma unroll
            for (int q = 0; q < 4; ++q) {
                int row = row0 + rf * 16 + (l >> 4) * 4 + q;
                float v = acc[rf][cfi][q] + bv;
                if (RELU) v = fmaxf(v, 0.f);
                if (row < N) out[(size_t)row * 128 + col] = v;
            }
        }
}

extern "C" void kernel_launch(void* const* d_in, const int* in_sizes, int n_in,
                              void* d_out, int out_size, void* d_ws, size_t ws_size,
                              hipStream_t stream) {
    const float* x       = (const float*)d_in[0];
    const int*   src     = (const int*)d_in[1];
    const int*   dst     = (const int*)d_in[2];
    const float* Wself1  = (const float*)d_in[3];
    const float* Wneigh1 = (const float*)d_in[4];
    const float* b1      = (const float*)d_in[5];
    const float* Wself2  = (const float*)d_in[6];
    const float* Wneigh2 = (const float*)d_in[7];
    const float* b2      = (const float*)d_in[8];
    float* out = (float*)d_out;

    const int N = in_sizes[0] / 128;
    const int E = in_sizes[1];

    char* p = (char*)d_ws;
    auto alloc = [&](size_t bytes) {
        char* r = p;
        p += (bytes + 255) & ~(size_t)255;
        return r;
    };
    int*   deg     = (int*)alloc((size_t)N * 4);
    int*   row_ptr = (int*)alloc((size_t)(N + 1) * 4);
    int*   cursor  = (int*)alloc((size_t)N * 4);
    int*   part    = (int*)alloc((size_t)N * 4);
    int*   bsum    = (int*)alloc(64 * 4);
    int*   ssrc    = (int*)alloc((size_t)E * 4);
    float* hn      = (float*)alloc((size_t)N * 128 * 4);
    float* h1      = (float*)alloc((size_t)N * 128 * 4);
    unsigned short* ws1pk = (unsigned short*)alloc(65536);  // 4096 frags x 16B each
    unsigned short* wn1pk = (unsigned short*)alloc(65536);
    unsigned short* ws2pk = (unsigned short*)alloc(65536);
    unsigned short* wn2pk = (unsigned short*)alloc(65536);
    (void)ws_size;

    const int nb1 = (N + 2047) / 2048;  // 25 (must be <= 64)

    // CSR build
    zero_i32<<<(N + 255) / 256, 256, 0, stream>>>(deg, N);
    degree_kernel<<<(E + 255) / 256, 256, 0, stream>>>(dst, deg, E);
    scan1<<<nb1, 256, 0, stream>>>(deg, part, bsum, N);
    scan2<<<1, 64, 0, stream>>>(bsum, row_ptr + N, nb1);
    scan3<<<(N + 255) / 256, 256, 0, stream>>>(part, bsum, row_ptr, cursor, N);
    scatter_kernel<<<(E + 255) / 256, 256, 0, stream>>>(src, dst, cursor, ssrc, E);

    // Weight split+pack (hi/lo bf16, B-fragment order)
    pack_w<<<64, 256, 0, stream>>>(Wself1, Wneigh1, Wself2, Wneigh2,
                                   ws1pk, wn1pk, ws2pk, wn2pk);

    int agg_blocks = (int)(((size_t)N * 32 + 255) / 256);
    int gemm_blocks = (N + 63) / 64;

    // Layer 1
    agg_kernel<<<agg_blocks, 256, 0, stream>>>(x, row_ptr, ssrc, hn, N);
    gemm_mfma<1><<<gemm_blocks, 256, 0, stream>>>(x, hn, ws1pk, wn1pk, b1, h1, N);

    // Layer 2
    agg_kernel<<<agg_blocks, 256, 0, stream>>>(h1, row_ptr, ssrc, hn, N);
    gemm_mfma<0><<<gemm_blocks, 256, 0, stream>>>(h1, hn, ws2pk, wn2pk, b2, out, N);
}